// Round 4
// baseline (45.133 us; speedup 1.0000x reference)
//
#include <hip/hip_runtime.h>

#define E 1280
#define H 20
#define L 8192
#define D 64
#define CHUNK 128
#define NCHUNK (L / CHUNK)   // 64

typedef float f4 __attribute__((ext_vector_type(4)));   // clang-native for nontemporal

// ---------------------------------------------------------------- K1: QKV GEMVs
// 3*E rows; one wave (64 lanes) per row; block = 256 = 4 rows.
__global__ void qkv_kernel(const float* __restrict__ hs,
                           const float* __restrict__ Wq, const float* __restrict__ bq,
                           const float* __restrict__ Wk,
                           const float* __restrict__ Wv, const float* __restrict__ bv,
                           float* __restrict__ qkv) {
    int row_global = blockIdx.x * 4 + (threadIdx.x >> 6);   // 0..3839
    int lane = threadIdx.x & 63;
    int mat = row_global / E;     // 0=q, 1=k, 2=v
    int row = row_global - mat * E;
    const float* W = (mat == 0) ? Wq : (mat == 1) ? Wk : Wv;
    const float4* Wrow = (const float4*)(W + (size_t)row * E);
    const float4* h4 = (const float4*)hs;
    float sum = 0.f;
#pragma unroll
    for (int i = 0; i < 5; ++i) {              // 320 float4 per row / 64 lanes
        int idx = lane + 64 * i;
        float4 w4 = Wrow[idx];
        float4 x4 = h4[idx];
        sum += w4.x * x4.x + w4.y * x4.y + w4.z * x4.z + w4.w * x4.w;
    }
#pragma unroll
    for (int off = 32; off > 0; off >>= 1) sum += __shfl_down(sum, off, 64);
    if (lane == 0) {
        float val;
        if (mat == 0)      val = (sum + bq[row]) * 0.125f;   // scale = 64^-0.5
        else if (mat == 1) val = sum;                        // k: no bias
        else               val = sum + bv[row];
        qkv[mat * E + row] = val;
    }
}

// ---------------------------------------------------------------- K2: fused K+V pass
// grid = H*NCHUNK = 1280 blocks of 256 (exactly 5 blocks/CU).
// Thread layout: cc = tid&15 (d-slice, float4), rg = tid>>4 (row group 0..15).
// Pass 1 streams K (no cross-lane ops in loop): per-lane partial dots -> padded
// LDS. Batched reduce computes scores/max/exp. Pass 2 streams V with LDS
// broadcast weight. Cross-lane reduction only once at the end.
__global__ void kv_kernel(const float* __restrict__ kc, const float* __restrict__ vc,
                          const float* __restrict__ qkv, const int* __restrict__ pos_p,
                          float* __restrict__ out_k, float* __restrict__ out_v,
                          float* __restrict__ cmax, float* __restrict__ csum,
                          float* __restrict__ o_part) {
    int h = blockIdx.x / NCHUNK;
    int c = blockIdx.x - h * NCHUNK;
    int pos = pos_p[0];
    int tid = threadIdx.x;
    int wave = tid >> 6;
    int lane = tid & 63;
    int cc = tid & 15;
    int rg = tid >> 4;            // 0..15

    __shared__ float s_part[CHUNK][17];   // padded partial dots (8.5 KB)
    __shared__ float s_w[CHUNK];          // exp weights
    __shared__ float smax4[4];
    __shared__ float spsum[4];
    __shared__ float sacc[4][D];

    float4 q4  = ((const float4*)qkv)[h * 16 + cc];
    float4 kn4 = ((const float4*)(qkv + E))[h * 16 + cc];
    float4 vn4 = ((const float4*)(qkv + 2 * E))[h * 16 + cc];

    size_t base = ((size_t)h * L + (size_t)c * CHUNK) * D;
    const float* kbase = kc + base;
    const float* vbase = vc + base;
    float* okbase = out_k + base;
    float* ovbase = out_v + base;
    int l0 = c * CHUNK;

    // ---- pass 1: stream K, copy, per-lane partial dot -> LDS
#pragma unroll
    for (int it = 0; it < CHUNK / 16; ++it) {     // 8
        int r = it * 16 + rg;
        int l = l0 + r;
        float4 k4 = ((const float4*)(kbase + r * D))[cc];
        if (l == pos) k4 = kn4;
        f4 kv = {k4.x, k4.y, k4.z, k4.w};
        __builtin_nontemporal_store(kv, (f4*)(okbase + r * D) + cc);
        s_part[r][cc] = k4.x * q4.x + k4.y * q4.y + k4.z * q4.z + k4.w * q4.w;
    }
    __syncthreads();

    // ---- batched reduce: threads 0..127 each own one row
    float s = -INFINITY;
    if (tid < CHUNK) {
        float sum = 0.f;
#pragma unroll
        for (int i = 0; i < 16; ++i) sum += s_part[tid][i];
        s = (l0 + tid <= pos) ? sum : -INFINITY;
    }
    float lm = s;
#pragma unroll
    for (int off = 32; off > 0; off >>= 1)
        lm = fmaxf(lm, __shfl_xor(lm, off, 64));
    if (lane == 0) smax4[wave] = lm;
    __syncthreads();
    float m = fmaxf(fmaxf(smax4[0], smax4[1]), fmaxf(smax4[2], smax4[3]));

    float p = 0.f;
    if (tid < CHUNK) {
        p = (s > -1e30f) ? __expf(s - m) : 0.f;
        s_w[tid] = p;
    }
    float ps = p;
#pragma unroll
    for (int off = 32; off > 0; off >>= 1) ps += __shfl_xor(ps, off, 64);
    if (lane == 0) spsum[wave] = ps;
    __syncthreads();   // s_w + spsum visible

    // ---- pass 2: stream V, copy, weighted accumulate (LDS broadcast weight)
    float4 acc = {0.f, 0.f, 0.f, 0.f};
#pragma unroll
    for (int it = 0; it < CHUNK / 16; ++it) {
        int r = it * 16 + rg;
        int l = l0 + r;
        float4 v4 = ((const float4*)(vbase + r * D))[cc];
        if (l == pos) v4 = vn4;
        f4 vv = {v4.x, v4.y, v4.z, v4.w};
        __builtin_nontemporal_store(vv, (f4*)(ovbase + r * D) + cc);
        float w = s_w[r];
        acc.x += w * v4.x; acc.y += w * v4.y; acc.z += w * v4.z; acc.w += w * v4.w;
    }
    // reduce across the 4 row-groups within wave (lanes ^16, ^32)
    acc.x += __shfl_xor(acc.x, 16, 64); acc.y += __shfl_xor(acc.y, 16, 64);
    acc.z += __shfl_xor(acc.z, 16, 64); acc.w += __shfl_xor(acc.w, 16, 64);
    acc.x += __shfl_xor(acc.x, 32, 64); acc.y += __shfl_xor(acc.y, 32, 64);
    acc.z += __shfl_xor(acc.z, 32, 64); acc.w += __shfl_xor(acc.w, 32, 64);
    if ((lane >> 4) == 0) ((float4*)&sacc[wave][cc * 4])[0] = acc;
    __syncthreads();
    if (tid < D) {
        float o = sacc[0][tid] + sacc[1][tid] + sacc[2][tid] + sacc[3][tid];
        o_part[((size_t)h * NCHUNK + c) * D + tid] = o;
        if (tid == 0) {
            cmax[h * NCHUNK + c] = m;
            csum[h * NCHUNK + c] = spsum[0] + spsum[1] + spsum[2] + spsum[3];
        }
    }
}

// ---------------------------------------------------------------- K3: cross-chunk combine
__global__ void combine_kernel(const float* __restrict__ cmax, const float* __restrict__ csum,
                               const float* __restrict__ o_part, float* __restrict__ attn_out) {
    int h = blockIdx.x;
    int d = threadIdx.x;              // 64 threads
    float m = -INFINITY;
#pragma unroll
    for (int c = 0; c < NCHUNK; ++c) m = fmaxf(m, cmax[h * NCHUNK + c]);
    float denom = 0.f, o = 0.f;
#pragma unroll 4
    for (int c = 0; c < NCHUNK; ++c) {
        float mc = cmax[h * NCHUNK + c];
        float sc = (mc > -1e30f) ? __expf(mc - m) : 0.f;
        denom += csum[h * NCHUNK + c] * sc;
        o += o_part[((size_t)h * NCHUNK + c) * D + d] * sc;
    }
    attn_out[h * D + d] = o / denom;
}

// ---------------------------------------------------------------- K4: output GEMV
__global__ void ogemv_kernel(const float* __restrict__ attn_out, const float* __restrict__ Wo,
                             const float* __restrict__ bo, float* __restrict__ out) {
    int row = blockIdx.x * 4 + (threadIdx.x >> 6);
    int lane = threadIdx.x & 63;
    const float4* Wrow = (const float4*)(Wo + (size_t)row * E);
    const float4* x4 = (const float4*)attn_out;
    float sum = 0.f;
#pragma unroll
    for (int i = 0; i < 5; ++i) {
        int idx = lane + 64 * i;
        float4 w4 = Wrow[idx];
        float4 a4 = x4[idx];
        sum += w4.x * a4.x + w4.y * a4.y + w4.z * a4.z + w4.w * a4.w;
    }
#pragma unroll
    for (int off = 32; off > 0; off >>= 1) sum += __shfl_down(sum, off, 64);
    if (lane == 0) out[row] = sum + bo[row];
}

extern "C" void kernel_launch(void* const* d_in, const int* in_sizes, int n_in,
                              void* d_out, int out_size, void* d_ws, size_t ws_size,
                              hipStream_t stream) {
    const float* hs  = (const float*)d_in[0];
    const int*   pos = (const int*)d_in[1];    // int64 little-endian: low word ok (0<=pos<8192)
    const float* kc  = (const float*)d_in[2];
    const float* vc  = (const float*)d_in[3];
    const float* Wq  = (const float*)d_in[4];
    const float* bq  = (const float*)d_in[5];
    const float* Wk  = (const float*)d_in[6];
    const float* Wv  = (const float*)d_in[7];
    const float* bv  = (const float*)d_in[8];
    const float* Wo  = (const float*)d_in[9];
    const float* bo  = (const float*)d_in[10];

    float* out   = (float*)d_out;                 // [0 : E)        attention output
    float* out_k = out + E;                       // new_k_cache  (H*L*D)
    float* out_v = out_k + (size_t)H * L * D;     // new_v_cache

    float* ws       = (float*)d_ws;
    float* qkv      = ws;                             // 3*E
    float* cmax     = qkv + 3 * E;                    // H*NCHUNK
    float* csum     = cmax + H * NCHUNK;              // H*NCHUNK
    float* o_part   = csum + H * NCHUNK;              // H*NCHUNK*D
    float* attn_out = o_part + (size_t)H * NCHUNK * D;  // E

    qkv_kernel<<<3 * E / 4, 256, 0, stream>>>(hs, Wq, bq, Wk, Wv, bv, qkv);
    kv_kernel<<<H * NCHUNK, 256, 0, stream>>>(kc, vc, qkv, pos, out_k, out_v,
                                              cmax, csum, o_part);
    combine_kernel<<<H, 64, 0, stream>>>(cmax, csum, o_part, attn_out);
    ogemv_kernel<<<E / 4, 256, 0, stream>>>(attn_out, Wo, bo, out);
}